// Round 4
// baseline (4616.568 us; speedup 1.0000x reference)
//
#include <hip/hip_runtime.h>
#include <cstdint>
#include <cstddef>

#define BB    512
#define WINN  512
#define DIN   128
#define HIDN  256
#define DOUTN 64
#define PLENN 64
#define G4    1024   // 4*HID
#define SCALE2LOG2E 2.88539008177793f   // 2*log2(e)

__device__ __forceinline__ float tanh_fast(float xx) {
  float e = __expf(2.0f * xx);
  return 1.0f - 2.0f * __builtin_amdgcn_rcpf(e + 1.0f);
}
__device__ __forceinline__ float sigmoid_fast(float xx) {
  return __builtin_amdgcn_rcpf(1.0f + __expf(-xx));
}
__device__ __forceinline__ ushort f2bf(float f) {
  uint32_t u = __float_as_uint(f);
  return (ushort)((u + 0x7fffu + ((u >> 16) & 1u)) >> 16);
}
__device__ __forceinline__ float bflo(uint32_t u) { return __uint_as_float(u << 16); }
__device__ __forceinline__ float bfhi(uint32_t u) { return __uint_as_float(u & 0xffff0000u); }

// ---------------- one-time weight prep ----------------
__global__ void prep_weights(const float* __restrict__ W, const float* __restrict__ W_ih,
                             const float* __restrict__ W_hh, const float* __restrict__ b_ih,
                             const float* __restrict__ b_hh, const float* __restrict__ Wd,
                             const float* __restrict__ V,
                             float* __restrict__ WT, float* __restrict__ WihT,
                             float* __restrict__ Wdt, float* __restrict__ bias,
                             float* __restrict__ m2vv)
{
  int i = blockIdx.x * 256 + threadIdx.x;
  if (i < 512 * 128) { int j = i >> 7, v = i & 127; WT[i] = W[v * 512 + j]; }
  if (i < 448 * 1024) {
    int k = i >> 10, g = i & 1023;
    WihT[i] = (k < 192) ? W_ih[g * 192 + k] : W_hh[g * 256 + (k - 192)];
  }
  if (i < 256 * 64) { int h = i >> 6, d = i & 63; Wdt[i] = Wd[d * 256 + h]; }
  if (i < 1024) bias[i] = b_ih[i] + b_hh[i];
  if (i < 128) m2vv[i] = -2.0f * V[i];
}

// ---------------- one-time x -> bf16 copy ----------------
__global__ __launch_bounds__(256) void convert_x(const float* __restrict__ x,
                                                 ushort* __restrict__ x16)
{
  size_t i = ((size_t)blockIdx.x * 256 + threadIdx.x) * 8;
  float4 a = *(const float4*)(x + i);
  float4 b = *(const float4*)(x + i + 4);
  uint4 o;
  o.x = (uint32_t)f2bf(a.x) | ((uint32_t)f2bf(a.y) << 16);
  o.y = (uint32_t)f2bf(a.z) | ((uint32_t)f2bf(a.w) << 16);
  o.z = (uint32_t)f2bf(b.x) | ((uint32_t)f2bf(b.y) << 16);
  o.w = (uint32_t)f2bf(b.z) | ((uint32_t)f2bf(b.w) << 16);
  *(uint4*)(x16 + i) = o;
}

// ---------------- one-time Uk' = bf16(2*log2e * einsum('vd,bwd->bvw')) ----------------
// LDS [k][r] pad 69 (write stride 276%32=20 -> 2-way, free); XOR swizzle for reads.
__global__ __launch_bounds__(256) void compute_uk(const float* __restrict__ x,
                                                  const float* __restrict__ U,
                                                  ushort* __restrict__ Uk16)
{
  __shared__ float xs[64][69];
  __shared__ float us[64][69];
  int tid = threadIdx.x;
  int rblk = blockIdx.x >> 1;
  int vhalf = blockIdx.x & 1;
  int r0g = rblk * 64;
  int v0g = vhalf * 64;
  int b  = r0g >> 9;
  int w0 = r0g & 511;
  int tr = tid & 15, tc = tid >> 4;
  float acc[4][4];
#pragma unroll
  for (int i = 0; i < 4; ++i)
#pragma unroll
    for (int j = 0; j < 4; ++j) acc[i][j] = 0.f;

  for (int ks = 0; ks < 2; ++ks) {
    int k0 = ks * 64;
#pragma unroll
    for (int i = 0; i < 4; ++i) {
      int idx = tid + i * 256;
      int r = idx >> 4, kq = idx & 15;
      float4 v4 = *(const float4*)(x + (size_t)(r0g + r) * 128 + k0 + kq * 4);
      int rb = r >> 2, cr = r & 3;
      xs[kq * 4 + 0][4 * (rb ^ ((kq * 4 + 0) & 3)) + cr] = v4.x;
      xs[kq * 4 + 1][4 * (rb ^ ((kq * 4 + 1) & 3)) + cr] = v4.y;
      xs[kq * 4 + 2][4 * (rb ^ ((kq * 4 + 2) & 3)) + cr] = v4.z;
      xs[kq * 4 + 3][4 * (rb ^ ((kq * 4 + 3) & 3)) + cr] = v4.w;
    }
#pragma unroll
    for (int i = 0; i < 4; ++i) {
      int idx = tid + i * 256;
      int v = idx >> 4, kq = idx & 15;
      float4 v4 = *(const float4*)(U + (size_t)(v0g + v) * 128 + k0 + kq * 4);
      int vb = v >> 2, cv = v & 3;
      us[kq * 4 + 0][4 * (vb ^ ((kq * 4 + 0) & 3)) + cv] = v4.x;
      us[kq * 4 + 1][4 * (vb ^ ((kq * 4 + 1) & 3)) + cv] = v4.y;
      us[kq * 4 + 2][4 * (vb ^ ((kq * 4 + 2) & 3)) + cv] = v4.z;
      us[kq * 4 + 3][4 * (vb ^ ((kq * 4 + 3) & 3)) + cv] = v4.w;
    }
    __syncthreads();
#pragma unroll 4
    for (int k = 0; k < 64; ++k) {
      float4 xr = *(const float4*)&xs[k][4 * (tr ^ (k & 3))];
      float4 ur = *(const float4*)&us[k][4 * (tc ^ (k & 3))];
      float xa[4] = {xr.x, xr.y, xr.z, xr.w};
      float ua[4] = {ur.x, ur.y, ur.z, ur.w};
#pragma unroll
      for (int i = 0; i < 4; ++i)
#pragma unroll
        for (int j = 0; j < 4; ++j) acc[i][j] = fmaf(xa[i], ua[j], acc[i][j]);
    }
    __syncthreads();
  }
#pragma unroll
  for (int j = 0; j < 4; ++j) {
    ushort4 o;
    o.x = f2bf(acc[0][j] * SCALE2LOG2E); o.y = f2bf(acc[1][j] * SCALE2LOG2E);
    o.z = f2bf(acc[2][j] * SCALE2LOG2E); o.w = f2bf(acc[3][j] * SCALE2LOG2E);
    *(ushort4*)(Uk16 + ((size_t)b * 128 + v0g + tc * 4 + j) * 512 + w0 + tr * 4) = o;
  }
}

// ---------------- per-step K2: lstm(t-1) + wq(half) + partial e over 64 v ----------------
// grid 1024 = (b, half); block 512
__global__ __launch_bounds__(512, 8) void e_half(const ushort* __restrict__ Uk16,
    const float* __restrict__ g0, const float* __restrict__ g1,
    float* __restrict__ s, const float* __restrict__ c_in, float* __restrict__ c_out,
    float* __restrict__ y, const float* __restrict__ WT, const float* __restrict__ Wdt,
    const float* __restrict__ bd, const float* __restrict__ m2vv_g,
    float* __restrict__ e_part, float* __restrict__ outy, int t)
{
  __shared__ float q_sh[512];
  __shared__ float mv_sh[64];
  __shared__ float tq_sh[64];
  __shared__ float wqp[8][66];
  __shared__ float scratch[4096];
  int tid = threadIdx.x;
  int b = blockIdx.x >> 1;
  int half = blockIdx.x & 1;

  // ---- prologue: lstm (both halves compute; half0 writes state) ----
  if (t > 0) {
    if (tid < 256) {
      int h = tid;
      size_t gb = (size_t)b * 1024;
      float gi = g0[gb + h]       + g1[gb + h];
      float gf = g0[gb + 256 + h] + g1[gb + 256 + h];
      float gg = g0[gb + 512 + h] + g1[gb + 512 + h];
      float go = g0[gb + 768 + h] + g1[gb + 768 + h];
      float cv = c_in[b * 256 + h];
      float cn = sigmoid_fast(gf) * cv + sigmoid_fast(gi) * tanh_fast(gg);
      float sn = sigmoid_fast(go) * tanh_fast(cn);
      q_sh[h] = sn;
      q_sh[256 + h] = cn;
      if (half == 0) { c_out[b * 256 + h] = cn; s[b * 256 + h] = sn; }
    }
  } else {
    if (tid < 256) { q_sh[tid] = 0.f; q_sh[256 + tid] = 0.f; }
  }
  if (tid >= 256 && tid < 320) mv_sh[tid - 256] = m2vv_g[half * 64 + (tid - 256)];
  __syncthreads();

  // ---- wq partials for this half's 64 v (8-way split over j) ----
  {
    int p = tid >> 6, v = tid & 63;
    float a = 0.f;
    const float* wtp = WT + (size_t)(p * 64) * 128 + half * 64 + v;
#pragma unroll 4
    for (int j = 0; j < 64; ++j) a = fmaf(q_sh[p * 64 + j], wtp[j * 128], a);
    wqp[p][v] = a;
  }
  __syncthreads();
  if (tid < 64) {
    float a = 0.f;
#pragma unroll
    for (int p = 0; p < 8; ++p) a += wqp[p][tid];
    tq_sh[tid] = SCALE2LOG2E * a;
  }
  // y = s_new @ Wd^T + bd (half0 only, one wave, full dots)
  if (half == 0 && t > 0 && tid >= 64 && tid < 128) {
    int d = tid - 64;
    float a = bd[d];
#pragma unroll 4
    for (int k = 0; k < 256; ++k) a = fmaf(q_sh[k], Wdt[k * 64 + d], a);
    y[b * 64 + d] = a;
    outy[(size_t)b * PLENN * 64 + (size_t)(t - 1) * 64 + d] = a;
  }
  __syncthreads();

  // ---- partial e: 8 vgroups x 8 v, 64 wc x 8 w; u' = 2log2e*u preloaded scale ----
  {
    int vg = tid >> 6, wc = tid & 63;
    float a8[8];
#pragma unroll
    for (int i = 0; i < 8; ++i) a8[i] = 0.f;
    const ushort* up = Uk16 + ((size_t)(b * 128 + half * 64 + vg * 8)) * 512 + wc * 8;
#pragma unroll
    for (int vi = 0; vi < 8; ++vi) {
      uint4 raw = *(const uint4*)(up + (size_t)vi * 512);
      float tq = tq_sh[vg * 8 + vi];
      float mv = mv_sh[vg * 8 + vi];
      a8[0] = fmaf(mv, __builtin_amdgcn_rcpf(__builtin_amdgcn_exp2f(bflo(raw.x) + tq) + 1.f), a8[0]);
      a8[1] = fmaf(mv, __builtin_amdgcn_rcpf(__builtin_amdgcn_exp2f(bfhi(raw.x) + tq) + 1.f), a8[1]);
      a8[2] = fmaf(mv, __builtin_amdgcn_rcpf(__builtin_amdgcn_exp2f(bflo(raw.y) + tq) + 1.f), a8[2]);
      a8[3] = fmaf(mv, __builtin_amdgcn_rcpf(__builtin_amdgcn_exp2f(bfhi(raw.y) + tq) + 1.f), a8[3]);
      a8[4] = fmaf(mv, __builtin_amdgcn_rcpf(__builtin_amdgcn_exp2f(bflo(raw.z) + tq) + 1.f), a8[4]);
      a8[5] = fmaf(mv, __builtin_amdgcn_rcpf(__builtin_amdgcn_exp2f(bfhi(raw.z) + tq) + 1.f), a8[5]);
      a8[6] = fmaf(mv, __builtin_amdgcn_rcpf(__builtin_amdgcn_exp2f(bflo(raw.w) + tq) + 1.f), a8[6]);
      a8[7] = fmaf(mv, __builtin_amdgcn_rcpf(__builtin_amdgcn_exp2f(bfhi(raw.w) + tq) + 1.f), a8[7]);
    }
    int rot = (wc + (wc >> 3)) & 7;
    int sbase = vg * 512 + wc * 8;
#pragma unroll
    for (int i = 0; i < 8; ++i) scratch[sbase + ((i + rot) & 7)] = a8[i];
  }
  __syncthreads();
  {
    float e = 0.f;
    int addr = (tid & ~7) + ((tid + (tid >> 3) + (tid >> 6)) & 7);
#pragma unroll
    for (int g = 0; g < 8; ++g) e += scratch[g * 512 + addr];
    e_part[(size_t)blockIdx.x * 512 + tid] = e;
  }
}

// ---------------- per-step K3: softmax (redundant per half) + partial ctx over 256 w ----------------
// grid 1024 = (b, half); block 512
__global__ __launch_bounds__(512, 8) void sm_ctx(const ushort* __restrict__ x16,
    const float* __restrict__ e_part, float* __restrict__ ctx_part,
    float* __restrict__ wout, int t)
{
  __shared__ float watt[512];
  __shared__ float red[16];
  __shared__ float cp2[544];
  __shared__ float scratch[4096];
  int tid = threadIdx.x;
  int b = blockIdx.x >> 1;
  int half = blockIdx.x & 1;

  float e = e_part[(size_t)b * 1024 + tid] + e_part[(size_t)b * 1024 + 512 + tid];
  float m = e;
#pragma unroll
  for (int o = 32; o > 0; o >>= 1) m = fmaxf(m, __shfl_xor(m, o));
  if ((tid & 63) == 0) red[tid >> 6] = m;
  __syncthreads();
  float M = red[0];
#pragma unroll
  for (int i2 = 1; i2 < 8; ++i2) M = fmaxf(M, red[i2]);
  float p = __expf(e - M);
  float wsum = p;
#pragma unroll
  for (int o = 32; o > 0; o >>= 1) wsum += __shfl_xor(wsum, o);
  if ((tid & 63) == 0) red[8 + (tid >> 6)] = wsum;
  __syncthreads();
  float S = red[8] + red[9] + red[10] + red[11] + red[12] + red[13] + red[14] + red[15];
  float wv = p * __builtin_amdgcn_rcpf(S);
  watt[tid] = wv;
  if (half == 0) wout[(size_t)b * PLENN * 512 + (size_t)t * 512 + tid] = wv;
  __syncthreads();

  // ctx partial over this half's 256 w: 32 wchunks x 8 w, 16 dgroups x 8 d
  {
    int dg = tid & 15, wch = tid >> 4;
    float a8[8];
#pragma unroll
    for (int i = 0; i < 8; ++i) a8[i] = 0.f;
    const ushort* xp = x16 + ((size_t)(b * 512 + half * 256 + wch * 8)) * 128 + dg * 8;
#pragma unroll
    for (int wi = 0; wi < 8; ++wi) {
      uint4 raw = *(const uint4*)(xp + (size_t)wi * 128);
      float wgt = watt[half * 256 + wch * 8 + wi];
      a8[0] = fmaf(wgt, bflo(raw.x), a8[0]);
      a8[1] = fmaf(wgt, bfhi(raw.x), a8[1]);
      a8[2] = fmaf(wgt, bflo(raw.y), a8[2]);
      a8[3] = fmaf(wgt, bfhi(raw.y), a8[3]);
      a8[4] = fmaf(wgt, bflo(raw.z), a8[4]);
      a8[5] = fmaf(wgt, bfhi(raw.z), a8[5]);
      a8[6] = fmaf(wgt, bflo(raw.w), a8[6]);
      a8[7] = fmaf(wgt, bfhi(raw.w), a8[7]);
    }
    int rot = (dg + wch) & 7;
    int sbase = wch * 128 + dg * 8;
#pragma unroll
    for (int i = 0; i < 8; ++i) scratch[sbase + ((i + rot) & 7)] = a8[i];
  }
  __syncthreads();
  {
    int p2 = tid >> 7, d = tid & 127;
    float a = 0.f;
#pragma unroll
    for (int k = 0; k < 8; ++k) {
      int wch = p2 * 8 + k;
      a += scratch[wch * 128 + (d & ~7) + (((d & 7) + (d >> 3) + wch) & 7)];
    }
    cp2[p2 * 136 + d] = a;
  }
  __syncthreads();
  if (tid < 128)
    ctx_part[(size_t)blockIdx.x * 128 + tid] =
        cp2[tid] + cp2[136 + tid] + cp2[272 + tid] + cp2[408 + tid];
}

// ---------------- per-step gates GEMM: 32x64 tiles, 512 blocks ----------------
__global__ __launch_bounds__(256) void gates_gemm(const float* __restrict__ y,
    const float* __restrict__ ctx_part, const float* __restrict__ s,
    const float* __restrict__ WihT, const float* __restrict__ bias,
    float* __restrict__ g0, float* __restrict__ g1)
{
  __shared__ float As[32][36];
  __shared__ float Bs[32][68];
  int tid = threadIdx.x;
  int bm = blockIdx.x;
  int bn = blockIdx.y;
  int kz = blockIdx.z;
  int tr = tid & 15, tc = tid >> 4;
  float acc[2][4];
#pragma unroll
  for (int i = 0; i < 2; ++i)
#pragma unroll
    for (int j = 0; j < 4; ++j) acc[i][j] = 0.f;

  for (int kt = 0; kt < 7; ++kt) {
    int k0 = kz * 224 + kt * 32;
#pragma unroll
    for (int i = 0; i < 4; ++i) {
      int idx = tid + i * 256;
      int r = idx >> 5, kk = idx & 31;
      int bbb = bm * 32 + r;
      float vA;
      if (k0 < 64) vA = y[bbb * 64 + k0 + kk];
      else if (k0 < 192) {
        int kc = k0 - 64 + kk;
        vA = ctx_part[(size_t)(bbb * 2) * 128 + kc] + ctx_part[(size_t)(bbb * 2 + 1) * 128 + kc];
      } else vA = s[bbb * 256 + (k0 - 192) + kk];
      As[kk][r] = vA;
    }
#pragma unroll
    for (int i = 0; i < 8; ++i) {
      int idx = tid + i * 256;
      int kk = idx >> 6, cc = idx & 63;
      Bs[kk][cc] = WihT[(size_t)(k0 + kk) * 1024 + bn * 64 + cc];
    }
    __syncthreads();
#pragma unroll 8
    for (int kk = 0; kk < 32; ++kk) {
      float2 a2 = *(const float2*)&As[kk][tr * 2];
      float4 b4 = *(const float4*)&Bs[kk][tc * 4];
      acc[0][0] = fmaf(a2.x, b4.x, acc[0][0]);
      acc[0][1] = fmaf(a2.x, b4.y, acc[0][1]);
      acc[0][2] = fmaf(a2.x, b4.z, acc[0][2]);
      acc[0][3] = fmaf(a2.x, b4.w, acc[0][3]);
      acc[1][0] = fmaf(a2.y, b4.x, acc[1][0]);
      acc[1][1] = fmaf(a2.y, b4.y, acc[1][1]);
      acc[1][2] = fmaf(a2.y, b4.z, acc[1][2]);
      acc[1][3] = fmaf(a2.y, b4.w, acc[1][3]);
    }
    __syncthreads();
  }
  float* dst = kz ? g1 : g0;
#pragma unroll
  for (int i = 0; i < 2; ++i) {
    int bb = bm * 32 + tr * 2 + i;
    int g  = bn * 64 + tc * 4;
    float4 o4;
    o4.x = acc[i][0] + (kz == 0 ? bias[g + 0] : 0.f);
    o4.y = acc[i][1] + (kz == 0 ? bias[g + 1] : 0.f);
    o4.z = acc[i][2] + (kz == 0 ? bias[g + 2] : 0.f);
    o4.w = acc[i][3] + (kz == 0 ? bias[g + 3] : 0.f);
    *(float4*)(dst + (size_t)bb * 1024 + g) = o4;
  }
}

// ---------------- tail: final lstm + y ----------------
__global__ __launch_bounds__(256) void lstm_tail(const float* __restrict__ g0,
    const float* __restrict__ g1, const float* __restrict__ c_in,
    const float* __restrict__ Wdt, const float* __restrict__ bd,
    float* __restrict__ outy, int t)
{
  __shared__ float ssh[256];
  int b = blockIdx.x, h = threadIdx.x;
  size_t gb = (size_t)b * 1024;
  float gi = g0[gb + h]       + g1[gb + h];
  float gf = g0[gb + 256 + h] + g1[gb + 256 + h];
  float gg = g0[gb + 512 + h] + g1[gb + 512 + h];
  float go = g0[gb + 768 + h] + g1[gb + 768 + h];
  float cv = c_in[b * 256 + h];
  float cn = sigmoid_fast(gf) * cv + sigmoid_fast(gi) * tanh_fast(gg);
  float sn = sigmoid_fast(go) * tanh_fast(cn);
  ssh[h] = sn;
  __syncthreads();
  if (h < 64) {
    float a = bd[h];
#pragma unroll 4
    for (int k = 0; k < 256; ++k) a = fmaf(ssh[k], Wdt[k * 64 + h], a);
    outy[(size_t)b * PLENN * 64 + (size_t)t * 64 + h] = a;
  }
}

extern "C" void kernel_launch(void* const* d_in, const int* in_sizes, int n_in,
                              void* d_out, int out_size, void* d_ws, size_t ws_size,
                              hipStream_t stream)
{
  (void)in_sizes; (void)n_in; (void)out_size; (void)ws_size;
  const float* x    = (const float*)d_in[0];
  const float* V    = (const float*)d_in[2];
  const float* W    = (const float*)d_in[3];
  const float* U    = (const float*)d_in[4];
  const float* W_ih = (const float*)d_in[5];
  const float* W_hh = (const float*)d_in[6];
  const float* b_ih = (const float*)d_in[7];
  const float* b_hh = (const float*)d_in[8];
  const float* Wd   = (const float*)d_in[9];
  const float* bd   = (const float*)d_in[10];

  float* out  = (float*)d_out;
  float* outy = out;                                   // predict_y (B,64,64)
  float* outw = out + (size_t)BB * PLENN * DOUTN;      // weight    (B,64,512)

  float* ws = (float*)d_ws;
  size_t o = 0;
  ushort* Uk16 = (ushort*)(ws + o); o += (size_t)BB * DIN * WINN / 2;
  ushort* x16  = (ushort*)(ws + o); o += (size_t)BB * WINN * DIN / 2;
  float* WT   = ws + o; o += 512 * 128;
  float* WihT = ws + o; o += 448 * 1024;
  float* Wdt  = ws + o; o += 256 * 64;
  float* bias = ws + o; o += 1024;
  float* m2vv = ws + o; o += 128;
  float* sbuf = ws + o; o += (size_t)BB * HIDN;
  float* cbuf = ws + o; o += (size_t)2 * BB * HIDN;   // ping-pong
  float* ybuf = ws + o; o += (size_t)BB * DOUTN;
  float* e_part   = ws + o; o += (size_t)1024 * 512;
  float* ctx_part = ws + o; o += (size_t)1024 * 128;
  float* g0   = ws + o; o += (size_t)BB * G4;
  float* g1   = ws + o; o += (size_t)BB * G4;

  hipMemsetAsync(sbuf, 0, (size_t)BB * HIDN * sizeof(float), stream);
  hipMemsetAsync(cbuf, 0, (size_t)2 * BB * HIDN * sizeof(float), stream);
  hipMemsetAsync(ybuf, 0, (size_t)BB * DOUTN * sizeof(float), stream);

  prep_weights<<<1792, 256, 0, stream>>>(W, W_ih, W_hh, b_ih, b_hh, Wd, V,
                                         WT, WihT, Wdt, bias, m2vv);
  convert_x<<<16384, 256, 0, stream>>>(x, x16);
  compute_uk<<<8192, 256, 0, stream>>>(x, U, Uk16);

  for (int t = 0; t < PLENN; ++t) {
    const float* cin = cbuf + (size_t)((t + 1) & 1) * BB * HIDN;  // = cbuf[(t-1)&1]
    float* cout      = cbuf + (size_t)(t & 1) * BB * HIDN;
    e_half<<<1024, 512, 0, stream>>>(Uk16, g0, g1, sbuf, cin, cout, ybuf,
                                     WT, Wdt, bd, m2vv, e_part, outy, t);
    sm_ctx<<<1024, 512, 0, stream>>>(x16, e_part, ctx_part, outw, t);
    gates_gemm<<<dim3(16, 16, 2), 256, 0, stream>>>(ybuf, ctx_part, sbuf, WihT, bias, g0, g1);
  }
  lstm_tail<<<BB, 256, 0, stream>>>(g0, g1, cbuf + (size_t)((PLENN - 1) & 1) * BB * HIDN,
                                    Wdt, bd, outy, PLENN - 1);
}

// Round 5
// 4281.069 us; speedup vs baseline: 1.0784x; 1.0784x over previous
//
#include <hip/hip_runtime.h>
#include <cstdint>
#include <cstddef>

#define BB    512
#define WINN  512
#define DIN   128
#define HIDN  256
#define DOUTN 64
#define PLENN 64
#define G4    1024   // 4*HID
#define SCALE2LOG2E 2.88539008177793f   // 2*log2(e)

typedef short bf16x8 __attribute__((ext_vector_type(8)));
typedef float f32x4 __attribute__((ext_vector_type(4)));

__device__ __forceinline__ float tanh_fast(float xx) {
  float e = __expf(2.0f * xx);
  return 1.0f - 2.0f * __builtin_amdgcn_rcpf(e + 1.0f);
}
__device__ __forceinline__ float sigmoid_fast(float xx) {
  return __builtin_amdgcn_rcpf(1.0f + __expf(-xx));
}
__device__ __forceinline__ ushort f2bf(float f) {
  uint32_t u = __float_as_uint(f);
  return (ushort)((u + 0x7fffu + ((u >> 16) & 1u)) >> 16);
}
__device__ __forceinline__ float bflo(uint32_t u) { return __uint_as_float(u << 16); }
__device__ __forceinline__ float bfhi(uint32_t u) { return __uint_as_float(u & 0xffff0000u); }

// ---------------- one-time weight prep ----------------
__global__ void prep_weights(const float* __restrict__ W, const float* __restrict__ W_ih,
                             const float* __restrict__ W_hh, const float* __restrict__ b_ih,
                             const float* __restrict__ b_hh, const float* __restrict__ Wd,
                             const float* __restrict__ V, const float* __restrict__ U,
                             float* __restrict__ WT, float* __restrict__ WihT,
                             float* __restrict__ Wdt, float* __restrict__ bias,
                             float* __restrict__ m2vv,
                             ushort* __restrict__ Uh16, ushort* __restrict__ Ul16)
{
  int i = blockIdx.x * 256 + threadIdx.x;
  if (i < 512 * 128) { int j = i >> 7, v = i & 127; WT[i] = W[v * 512 + j]; }
  if (i < 448 * 1024) {
    int k = i >> 10, g = i & 1023;
    WihT[i] = (k < 192) ? W_ih[g * 192 + k] : W_hh[g * 256 + (k - 192)];
  }
  if (i < 256 * 64) { int h = i >> 6, d = i & 63; Wdt[i] = Wd[d * 256 + h]; }
  if (i < 1024) bias[i] = b_ih[i] + b_hh[i];
  if (i < 128) m2vv[i] = -2.0f * V[i];
  if (i < 128 * 128) {
    float us = SCALE2LOG2E * U[i];
    ushort h = f2bf(us);
    float lo = us - __uint_as_float((uint32_t)h << 16);
    Uh16[i] = h;
    Ul16[i] = f2bf(lo);
  }
}

// ---------------- one-time x -> bf16 copy ----------------
__global__ __launch_bounds__(256) void convert_x(const float* __restrict__ x,
                                                 ushort* __restrict__ x16)
{
  size_t i = ((size_t)blockIdx.x * 256 + threadIdx.x) * 8;
  float4 a = *(const float4*)(x + i);
  float4 b = *(const float4*)(x + i + 4);
  uint4 o;
  o.x = (uint32_t)f2bf(a.x) | ((uint32_t)f2bf(a.y) << 16);
  o.y = (uint32_t)f2bf(a.z) | ((uint32_t)f2bf(a.w) << 16);
  o.z = (uint32_t)f2bf(b.x) | ((uint32_t)f2bf(b.y) << 16);
  o.w = (uint32_t)f2bf(b.z) | ((uint32_t)f2bf(b.w) << 16);
  *(uint4*)(x16 + i) = o;
}

// ---------------- one-time Uk' = bf16( (Uh+Ul) @ x16^T ), MFMA, zero LDS ----------------
// Uk'[b][v][w] = 2log2e * sum_d U[v][d] x[b][w][d]; A=U-split (row-major, k-contig),
// B=x16 (row-major [w][d], k-contig). 16x16x32 bf16 MFMA; C/D: col=lane&15, row=(lane>>4)*4+r.
__global__ __launch_bounds__(256) void compute_uk_mfma(const ushort* __restrict__ x16,
                                                       const ushort* __restrict__ Uh16,
                                                       const ushort* __restrict__ Ul16,
                                                       ushort* __restrict__ Uk16)
{
  int bidx = blockIdx.x;
  int b   = bidx >> 3;
  int sub = bidx & 7;
  int vs  = sub >> 2;       // 0..1  (64-v strip)
  int wsb = sub & 3;        // 0..3  (128-w strip)
  int tid = threadIdx.x;
  int wave = tid >> 6;
  int lane = tid & 63;
  int lr = lane & 15;       // A-row / B-col
  int lk = lane >> 4;       // k subgroup

  int v_base = vs * 64 + wave * 16;
  int w_blk  = wsb * 128;

  bf16x8 ah[4], al[4];
#pragma unroll
  for (int kt = 0; kt < 4; ++kt) {
    const ushort* pa = Uh16 + (size_t)(v_base + lr) * 128 + kt * 32 + lk * 8;
    const ushort* pl = Ul16 + (size_t)(v_base + lr) * 128 + kt * 32 + lk * 8;
    ah[kt] = *(const bf16x8*)pa;
    al[kt] = *(const bf16x8*)pl;
  }

#pragma unroll 2
  for (int wt = 0; wt < 8; ++wt) {
    int w0 = w_blk + wt * 16;
    f32x4 acc = {0.f, 0.f, 0.f, 0.f};
#pragma unroll
    for (int kt = 0; kt < 4; ++kt) {
      const ushort* pb = x16 + ((size_t)b * 512 + w0 + lr) * 128 + kt * 32 + lk * 8;
      bf16x8 bv = *(const bf16x8*)pb;
      acc = __builtin_amdgcn_mfma_f32_16x16x32_bf16(ah[kt], bv, acc, 0, 0, 0);
      acc = __builtin_amdgcn_mfma_f32_16x16x32_bf16(al[kt], bv, acc, 0, 0, 0);
    }
#pragma unroll
    for (int r = 0; r < 4; ++r) {
      int v_out = v_base + lk * 4 + r;
      Uk16[((size_t)b * 128 + v_out) * 512 + w0 + lr] = f2bf(acc[r]);
    }
  }
}

// ---------------- fused per-step: lstm(t-1) + wq + e + softmax + ctx ----------------
__global__ __launch_bounds__(512, 6) void attn_fused(const ushort* __restrict__ Uk16,
    const ushort* __restrict__ x16, float* __restrict__ s, float* __restrict__ c,
    float* __restrict__ y, const float* __restrict__ g0, const float* __restrict__ g1,
    const float* __restrict__ WT, const float* __restrict__ Wdt,
    const float* __restrict__ bd, const float* __restrict__ m2vv_g,
    float* __restrict__ ctx, float* __restrict__ wout, float* __restrict__ outy, int t)
{
  __shared__ float q_sh[512];     // [s(256); c(256)]
  __shared__ float tqs[128];      // 2log2e * wq[v]
  __shared__ float m2vv[128];     // -2*V[v]
  __shared__ float watt[512];
  __shared__ float red[16];
  __shared__ float cp2[544];
  __shared__ float scratch[4096];
  int tid = threadIdx.x;
  int b = blockIdx.x;

  // ---- phase A: lstm(t-1) -> s,c, or zeros at t==0 ----
  if (t > 0) {
    if (tid < 256) {
      int h = tid;
      size_t gb = (size_t)b * 1024;
      float gi = g0[gb + h]       + g1[gb + h];
      float gf = g0[gb + 256 + h] + g1[gb + 256 + h];
      float gg = g0[gb + 512 + h] + g1[gb + 512 + h];
      float go = g0[gb + 768 + h] + g1[gb + 768 + h];
      float cv = c[b * 256 + h];
      float cn = sigmoid_fast(gf) * cv + sigmoid_fast(gi) * tanh_fast(gg);
      float sn = sigmoid_fast(go) * tanh_fast(cn);
      c[b * 256 + h] = cn;
      s[b * 256 + h] = sn;
      q_sh[h] = sn;
      q_sh[256 + h] = cn;
    }
  } else {
    if (tid < 256) { q_sh[tid] = 0.f; q_sh[256 + tid] = 0.f; }
  }
  if (tid >= 256 && tid < 384) m2vv[tid - 256] = m2vv_g[tid - 256];
  __syncthreads();

  // ---- phase A2: y partials (8-way over h) in scratch[0..543] ----
  if (t > 0) {
    int p = tid >> 6, d = tid & 63;
    float a = 0.f;
    const float* wdp = Wdt + (size_t)(p * 32) * 64 + d;
#pragma unroll 4
    for (int hh = 0; hh < 32; ++hh) a = fmaf(q_sh[p * 32 + hh], wdp[hh * 64], a);
    scratch[p * 68 + d] = a;
  }
  // ---- phase B1: wq partials (4-way over j) in scratch[1024..] ----
  {
    int p = tid >> 7, v = tid & 127;
    float a = 0.f;
    const float* wtp = WT + (size_t)(p * 128) * 128 + v;
#pragma unroll 4
    for (int j = 0; j < 128; ++j) a = fmaf(q_sh[p * 128 + j], wtp[j * 128], a);
    scratch[1024 + p * 132 + v] = a;
  }
  __syncthreads();
  if (t > 0 && tid < 64) {
    float a = bd[tid];
#pragma unroll
    for (int p = 0; p < 8; ++p) a += scratch[p * 68 + tid];
    y[b * 64 + tid] = a;
    outy[(size_t)b * PLENN * 64 + (size_t)(t - 1) * 64 + tid] = a;
  }
  if (tid >= 128 && tid < 256) {
    int v = tid - 128;
    float wq = scratch[1024 + v] + scratch[1024 + 132 + v] +
               scratch[1024 + 264 + v] + scratch[1024 + 396 + v];
    tqs[v] = SCALE2LOG2E * wq;
  }
  __syncthreads();

  // ---- phase C: e-partials; (vg=tid>>6, wc=tid&63): 16 v x 8 w each ----
  {
    int vg = tid >> 6, wc = tid & 63;
    float a8[8];
#pragma unroll
    for (int i = 0; i < 8; ++i) a8[i] = 0.f;
    const ushort* up = Uk16 + ((size_t)(b * 128 + vg * 16)) * 512 + wc * 8;
#pragma unroll 4
    for (int vi = 0; vi < 16; ++vi) {
      uint4 raw = *(const uint4*)(up + (size_t)vi * 512);
      float tq = tqs[vg * 16 + vi];
      float mv = m2vv[vg * 16 + vi];
      a8[0] = fmaf(mv, __builtin_amdgcn_rcpf(__builtin_amdgcn_exp2f(bflo(raw.x) + tq) + 1.f), a8[0]);
      a8[1] = fmaf(mv, __builtin_amdgcn_rcpf(__builtin_amdgcn_exp2f(bfhi(raw.x) + tq) + 1.f), a8[1]);
      a8[2] = fmaf(mv, __builtin_amdgcn_rcpf(__builtin_amdgcn_exp2f(bflo(raw.y) + tq) + 1.f), a8[2]);
      a8[3] = fmaf(mv, __builtin_amdgcn_rcpf(__builtin_amdgcn_exp2f(bfhi(raw.y) + tq) + 1.f), a8[3]);
      a8[4] = fmaf(mv, __builtin_amdgcn_rcpf(__builtin_amdgcn_exp2f(bflo(raw.z) + tq) + 1.f), a8[4]);
      a8[5] = fmaf(mv, __builtin_amdgcn_rcpf(__builtin_amdgcn_exp2f(bfhi(raw.z) + tq) + 1.f), a8[5]);
      a8[6] = fmaf(mv, __builtin_amdgcn_rcpf(__builtin_amdgcn_exp2f(bflo(raw.w) + tq) + 1.f), a8[6]);
      a8[7] = fmaf(mv, __builtin_amdgcn_rcpf(__builtin_amdgcn_exp2f(bfhi(raw.w) + tq) + 1.f), a8[7]);
    }
    int rot = (wc + (wc >> 3)) & 7;
    int sbase = vg * 512 + wc * 8;
#pragma unroll
    for (int i = 0; i < 8; ++i) scratch[sbase + ((i + rot) & 7)] = a8[i];
  }
  __syncthreads();
  float e = 0.f;
  {
    int addr = (tid & ~7) + ((tid + (tid >> 3) + (tid >> 6)) & 7);
#pragma unroll
    for (int g = 0; g < 8; ++g) e += scratch[g * 512 + addr];
  }

  // ---- softmax over 512 w ----
  float m = e;
#pragma unroll
  for (int o = 32; o > 0; o >>= 1) m = fmaxf(m, __shfl_xor(m, o));
  if ((tid & 63) == 0) red[tid >> 6] = m;
  __syncthreads();
  float M = red[0];
#pragma unroll
  for (int i2 = 1; i2 < 8; ++i2) M = fmaxf(M, red[i2]);
  float p = __expf(e - M);
  float wsum = p;
#pragma unroll
  for (int o = 32; o > 0; o >>= 1) wsum += __shfl_xor(wsum, o);
  if ((tid & 63) == 0) red[8 + (tid >> 6)] = wsum;
  __syncthreads();
  float S = red[8] + red[9] + red[10] + red[11] + red[12] + red[13] + red[14] + red[15];
  float wv = p * __builtin_amdgcn_rcpf(S);
  watt[tid] = wv;
  wout[(size_t)b * PLENN * 512 + (size_t)t * 512 + tid] = wv;
  __syncthreads();

  // ---- phase E: ctx partials; (wch=tid>>4, dg=tid&15): 16 w x 8 d each ----
  {
    int dg = tid & 15, wch = tid >> 4;
    float a8[8];
#pragma unroll
    for (int i = 0; i < 8; ++i) a8[i] = 0.f;
    const ushort* xp = x16 + ((size_t)(b * 512 + wch * 16)) * 128 + dg * 8;
#pragma unroll 4
    for (int wi = 0; wi < 16; ++wi) {
      uint4 raw = *(const uint4*)(xp + (size_t)wi * 128);
      float wgt = watt[wch * 16 + wi];
      a8[0] = fmaf(wgt, bflo(raw.x), a8[0]);
      a8[1] = fmaf(wgt, bfhi(raw.x), a8[1]);
      a8[2] = fmaf(wgt, bflo(raw.y), a8[2]);
      a8[3] = fmaf(wgt, bfhi(raw.y), a8[3]);
      a8[4] = fmaf(wgt, bflo(raw.z), a8[4]);
      a8[5] = fmaf(wgt, bfhi(raw.z), a8[5]);
      a8[6] = fmaf(wgt, bflo(raw.w), a8[6]);
      a8[7] = fmaf(wgt, bfhi(raw.w), a8[7]);
    }
    int rot = (dg + wch) & 7;
    int sbase = wch * 128 + dg * 8;
#pragma unroll
    for (int i = 0; i < 8; ++i) scratch[sbase + ((i + rot) & 7)] = a8[i];
  }
  __syncthreads();
  {
    int p2 = tid >> 7, d = tid & 127;
    float a = 0.f;
#pragma unroll
    for (int k = 0; k < 8; ++k) {
      int wch = p2 * 8 + k;
      a += scratch[wch * 128 + (d & ~7) + (((d & 7) + (d >> 3) + wch) & 7)];
    }
    cp2[p2 * 136 + d] = a;
  }
  __syncthreads();
  if (tid < 128)
    ctx[b * 128 + tid] = cp2[tid] + cp2[136 + tid] + cp2[272 + tid] + cp2[408 + tid];
}

// ---------------- per-step gates GEMM: 32x64 tiles, 512 blocks ----------------
__global__ __launch_bounds__(256) void gates_gemm(const float* __restrict__ y,
    const float* __restrict__ ctx, const float* __restrict__ s,
    const float* __restrict__ WihT, const float* __restrict__ bias,
    float* __restrict__ g0, float* __restrict__ g1)
{
  __shared__ float As[32][36];
  __shared__ float Bs[32][68];
  int tid = threadIdx.x;
  int bm = blockIdx.x;
  int bn = blockIdx.y;
  int kz = blockIdx.z;
  int tr = tid & 15, tc = tid >> 4;
  float acc[2][4];
#pragma unroll
  for (int i = 0; i < 2; ++i)
#pragma unroll
    for (int j = 0; j < 4; ++j) acc[i][j] = 0.f;

  for (int kt = 0; kt < 7; ++kt) {
    int k0 = kz * 224 + kt * 32;
    const float* Ab; int stride, off;
    if (k0 < 64)       { Ab = y;   stride = 64;  off = 0; }
    else if (k0 < 192) { Ab = ctx; stride = 128; off = 64; }
    else               { Ab = s;   stride = 256; off = 192; }
#pragma unroll
    for (int i = 0; i < 4; ++i) {
      int idx = tid + i * 256;
      int r = idx >> 5, kk = idx & 31;
      As[kk][r] = Ab[(size_t)(bm * 32 + r) * stride + (k0 - off) + kk];
    }
#pragma unroll
    for (int i = 0; i < 8; ++i) {
      int idx = tid + i * 256;
      int kk = idx >> 6, cc = idx & 63;
      Bs[kk][cc] = WihT[(size_t)(k0 + kk) * 1024 + bn * 64 + cc];
    }
    __syncthreads();
#pragma unroll 8
    for (int kk = 0; kk < 32; ++kk) {
      float2 a2 = *(const float2*)&As[kk][tr * 2];
      float4 b4 = *(const float4*)&Bs[kk][tc * 4];
      acc[0][0] = fmaf(a2.x, b4.x, acc[0][0]);
      acc[0][1] = fmaf(a2.x, b4.y, acc[0][1]);
      acc[0][2] = fmaf(a2.x, b4.z, acc[0][2]);
      acc[0][3] = fmaf(a2.x, b4.w, acc[0][3]);
      acc[1][0] = fmaf(a2.y, b4.x, acc[1][0]);
      acc[1][1] = fmaf(a2.y, b4.y, acc[1][1]);
      acc[1][2] = fmaf(a2.y, b4.z, acc[1][2]);
      acc[1][3] = fmaf(a2.y, b4.w, acc[1][3]);
    }
    __syncthreads();
  }
  float* dst = kz ? g1 : g0;
#pragma unroll
  for (int i = 0; i < 2; ++i) {
    int bb = bm * 32 + tr * 2 + i;
    int g  = bn * 64 + tc * 4;
    float4 o4;
    o4.x = acc[i][0] + (kz == 0 ? bias[g + 0] : 0.f);
    o4.y = acc[i][1] + (kz == 0 ? bias[g + 1] : 0.f);
    o4.z = acc[i][2] + (kz == 0 ? bias[g + 2] : 0.f);
    o4.w = acc[i][3] + (kz == 0 ? bias[g + 3] : 0.f);
    *(float4*)(dst + (size_t)bb * 1024 + g) = o4;
  }
}

// ---------------- tail: final lstm + y ----------------
__global__ __launch_bounds__(256) void lstm_tail(const float* __restrict__ g0,
    const float* __restrict__ g1, const float* __restrict__ c_in,
    const float* __restrict__ Wdt, const float* __restrict__ bd,
    float* __restrict__ outy, int t)
{
  __shared__ float ssh[256];
  int b = blockIdx.x, h = threadIdx.x;
  size_t gb = (size_t)b * 1024;
  float gi = g0[gb + h]       + g1[gb + h];
  float gf = g0[gb + 256 + h] + g1[gb + 256 + h];
  float gg = g0[gb + 512 + h] + g1[gb + 512 + h];
  float go = g0[gb + 768 + h] + g1[gb + 768 + h];
  float cv = c_in[b * 256 + h];
  float cn = sigmoid_fast(gf) * cv + sigmoid_fast(gi) * tanh_fast(gg);
  float sn = sigmoid_fast(go) * tanh_fast(cn);
  ssh[h] = sn;
  __syncthreads();
  if (h < 64) {
    float a = bd[h];
#pragma unroll 4
    for (int k = 0; k < 256; ++k) a = fmaf(ssh[k], Wdt[k * 64 + h], a);
    outy[(size_t)b * PLENN * 64 + (size_t)t * 64 + h] = a;
  }
}

extern "C" void kernel_launch(void* const* d_in, const int* in_sizes, int n_in,
                              void* d_out, int out_size, void* d_ws, size_t ws_size,
                              hipStream_t stream)
{
  (void)in_sizes; (void)n_in; (void)out_size; (void)ws_size;
  const float* x    = (const float*)d_in[0];
  const float* V    = (const float*)d_in[2];
  const float* W    = (const float*)d_in[3];
  const float* U    = (const float*)d_in[4];
  const float* W_ih = (const float*)d_in[5];
  const float* W_hh = (const float*)d_in[6];
  const float* b_ih = (const float*)d_in[7];
  const float* b_hh = (const float*)d_in[8];
  const float* Wd   = (const float*)d_in[9];
  const float* bd   = (const float*)d_in[10];

  float* out  = (float*)d_out;
  float* outy = out;                                   // predict_y (B,64,64)
  float* outw = out + (size_t)BB * PLENN * DOUTN;      // weight    (B,64,512)

  float* ws = (float*)d_ws;
  size_t o = 0;
  ushort* Uk16 = (ushort*)(ws + o); o += (size_t)BB * DIN * WINN / 2;
  ushort* x16  = (ushort*)(ws + o); o += (size_t)BB * WINN * DIN / 2;
  float* WT   = ws + o; o += 512 * 128;
  float* WihT = ws + o; o += 448 * 1024;
  float* Wdt  = ws + o; o += 256 * 64;
  float* bias = ws + o; o += 1024;
  float* m2vv = ws + o; o += 128;
  ushort* Uh16 = (ushort*)(ws + o); o += 128 * 128 / 2;
  ushort* Ul16 = (ushort*)(ws + o); o += 128 * 128 / 2;
  float* sbuf = ws + o; o += (size_t)BB * HIDN;
  float* cbuf = ws + o; o += (size_t)BB * HIDN;
  float* ybuf = ws + o; o += (size_t)BB * DOUTN;
  float* ctx  = ws + o; o += (size_t)BB * DIN;
  float* g0   = ws + o; o += (size_t)BB * G4;
  float* g1   = ws + o; o += (size_t)BB * G4;

  hipMemsetAsync(sbuf, 0, (size_t)BB * HIDN * sizeof(float), stream);
  hipMemsetAsync(cbuf, 0, (size_t)BB * HIDN * sizeof(float), stream);
  hipMemsetAsync(ybuf, 0, (size_t)BB * DOUTN * sizeof(float), stream);

  prep_weights<<<1792, 256, 0, stream>>>(W, W_ih, W_hh, b_ih, b_hh, Wd, V, U,
                                         WT, WihT, Wdt, bias, m2vv, Uh16, Ul16);
  convert_x<<<16384, 256, 0, stream>>>(x, x16);
  compute_uk_mfma<<<4096, 256, 0, stream>>>(x16, Uh16, Ul16, Uk16);

  for (int t = 0; t < PLENN; ++t) {
    attn_fused<<<BB, 512, 0, stream>>>(Uk16, x16, sbuf, cbuf, ybuf, g0, g1,
                                       WT, Wdt, bd, m2vv, ctx, outw, outy, t);
    gates_gemm<<<dim3(16, 16, 2), 256, 0, stream>>>(ybuf, ctx, sbuf, WihT, bias, g0, g1);
  }
  lstm_tail<<<BB, 256, 0, stream>>>(g0, g1, cbuf, Wdt, bd, outy, PLENN - 1);
}